// Round 9
// baseline (7959.079 us; speedup 1.0000x reference)
//
#include <hip/hip_runtime.h>
#include <hip/hip_bf16.h>

// QuantizedLinear: out[8192,11008] = x[8192,4096] @ dequant(W)^T
// Round 9: occupancy pivot. 256x256 tile, BK=32, dbuf LDS = 64KiB ->
// 2 blocks/CU (4 waves/SIMD) with __launch_bounds__(512,4). One barrier per
// K-tile; cross-block TLP hides per-wave stalls. New 4-slot swizzle
// phys = logical ^ ((row>>1)&3), both-sides (pre-swizzled global source).

#define IN_F   4096
#define OUT_F  11008
#define M_DIM  8192
#define NGROUP 32

typedef __bf16 bf16x8 __attribute__((ext_vector_type(8)));
typedef float  f32x4  __attribute__((ext_vector_type(4)));
typedef unsigned short u16;
typedef u16 u16x8v __attribute__((ext_vector_type(8)));

__device__ __forceinline__ u16 f2bf(float f) {
  union { float f; unsigned u; } v; v.f = f;
  unsigned u = v.u;
  return (u16)((u + 0x7fffu + ((u >> 16) & 1u)) >> 16);  // RNE
}

__device__ __forceinline__ void gload_lds16(const void* gsrc, void* ldst) {
  __builtin_amdgcn_global_load_lds(
      (const __attribute__((address_space(1))) void*)gsrc,
      (__attribute__((address_space(3))) void*)ldst, 16, 0, 0);
}

// ---------------- dequant: packed 4-bit -> bf16 W[out][in] -----------------
__global__ __launch_bounds__(256) void dequant_w(const int* __restrict__ qw,
                                                 const int* __restrict__ qz,
                                                 const float* __restrict__ sc,
                                                 u16* __restrict__ W) {
  const int total = (IN_F / 2) * OUT_F / 4;  // int4 chunks
  int stride = gridDim.x * blockDim.x;
  for (int idx = blockIdx.x * blockDim.x + threadIdx.x; idx < total; idx += stride) {
    int j = idx << 2;
    int o = j >> 11;
    int g = (j >> 6) & 31;
    float z = (float)qz[(o << 5) + g];
    float s = sc[(o << 5) + g];
    int4 q = ((const int4*)qw)[idx];
    int qs0 = q.x, qs1 = q.y, qs2 = q.z, qs3 = q.w;
    u16x8v w;
    w[0] = f2bf(((float)(qs0 & 15) - z) * s);
    w[1] = f2bf(((float)((qs0 >> 4) & 15) - z) * s);
    w[2] = f2bf(((float)(qs1 & 15) - z) * s);
    w[3] = f2bf(((float)((qs1 >> 4) & 15) - z) * s);
    w[4] = f2bf(((float)(qs2 & 15) - z) * s);
    w[5] = f2bf(((float)((qs2 >> 4) & 15) - z) * s);
    w[6] = f2bf(((float)(qs3 & 15) - z) * s);
    w[7] = f2bf(((float)((qs3 >> 4) & 15) - z) * s);
    ((u16x8v*)W)[idx] = w;
  }
}

// ---------------- x fp32 -> bf16 -------------------------------------------
__global__ __launch_bounds__(256) void cvt_x(const float* __restrict__ x,
                                             u16* __restrict__ Xb) {
  const int total = M_DIM * IN_F / 8;
  int stride = gridDim.x * blockDim.x;
  for (int idx = blockIdx.x * blockDim.x + threadIdx.x; idx < total; idx += stride) {
    float4 a = ((const float4*)x)[idx * 2];
    float4 b = ((const float4*)x)[idx * 2 + 1];
    u16x8v v;
    v[0] = f2bf(a.x); v[1] = f2bf(a.y); v[2] = f2bf(a.z); v[3] = f2bf(a.w);
    v[4] = f2bf(b.x); v[5] = f2bf(b.y); v[6] = f2bf(b.z); v[7] = f2bf(b.w);
    ((u16x8v*)Xb)[idx] = v;
  }
}

// ---------------- 256x256 bf16 GEMM, BK=32, 2 blocks/CU: C = A * B^T -------
// 8 waves 2Mx4N; wave tile 128x64 contiguous (rows wr*128.., cols wc*64..).
// Per tile: stage next tile -> other buf; 12 ds_read frags; 32 MFMA; 1 barrier.

#define BAR       __builtin_amdgcn_s_barrier()
#define SCHED0    __builtin_amdgcn_sched_barrier(0)
#define LGKM0     asm volatile("s_waitcnt lgkmcnt(0)" ::: "memory")
#define VMCNT0    asm volatile("s_waitcnt vmcnt(0)" ::: "memory")
#define PRIO(p)   __builtin_amdgcn_s_setprio(p)

__global__ __launch_bounds__(512, 4) void gemm256(const u16* __restrict__ A,
                                                  const u16* __restrict__ B,
                                                  float* __restrict__ C) {
  constexpr int K = IN_F, N = OUT_F;
  constexpr int NT = K / 32;  // 128 K-tiles
  __shared__ __align__(16) u16 sA[2][256 * 32];   // 16KB each
  __shared__ __align__(16) u16 sB[2][256 * 32];   // total 64KB -> 2 blocks/CU

  const int NTN = OUT_F / 256;           // 43
  const int NWG = (M_DIM / 256) * NTN;   // 1376 (divisible by 8)
  int bid = blockIdx.x;
  int wg  = (bid & 7) * (NWG / 8) + (bid >> 3);  // bijective XCD swizzle
  int tm = wg / NTN, tn = wg - tm * NTN;
  int m0 = tm * 256, n0 = tn * 256;

  int tid  = threadIdx.x;
  int lane = tid & 63;
  int wave = tid >> 6;
  int wr = wave >> 2, wc = wave & 3;

  // staging: thread covers row (tid>>2) of a 128-row issue, phys 16B slot tid&3.
  // phys slot s at row r holds logical slot s ^ ((r>>1)&3)  (involution).
  int rstage = tid >> 2;                               // 0..127
  int slot4  = tid & 3;
  int gslot  = ((slot4 ^ ((rstage >> 1) & 3)) << 3);   // global col elem (0..24)
  int ldsoff = rstage * 32 + (slot4 << 3);             // linear LDS elem
  const u16* Ag = A + (size_t)(m0 + rstage) * K + gslot;
  const u16* Bg = B + (size_t)(n0 + rstage) * K + gslot;

#define STAGE_A(cb, kt) do {                                      \
    const u16* _g = Ag + (kt) * 32;                               \
    u16* _l = sA[cb] + ldsoff;                                    \
    gload_lds16(_g, _l);                                          \
    gload_lds16(_g + (size_t)128 * K, _l + 128 * 32);             \
  } while (0)

#define STAGE_B(cb, kt) do {                                      \
    const u16* _g = Bg + (kt) * 32;                               \
    u16* _l = sB[cb] + ldsoff;                                    \
    gload_lds16(_g, _l);                                          \
    gload_lds16(_g + (size_t)128 * K, _l + 128 * 32);             \
  } while (0)

  // fragment reads: lane reads row base+(lane&15), k-quad q8=lane>>4 (0..3).
  // phys slot = q8 ^ ((lane&15)>>1 & 3)   (row bases are multiples of 16)
  int q8 = lane >> 4;
  int fl = ((lane & 15) >> 1) & 3;
  int sl = ((q8 ^ fl) << 3);                     // elems
  int abase = (wr * 128 + (lane & 15)) * 32 + sl;
  int bbase = (wc * 64 + (lane & 15)) * 32 + sl;

  bf16x8 a_[8], b_[4];
  f32x4 acc[8][4] = {};

#define LDA(cb) do {                                              \
    const u16* _p = sA[cb] + abase;                               \
    a_[0] = *(const bf16x8*)(_p);                                 \
    a_[1] = *(const bf16x8*)(_p + 512);                           \
    a_[2] = *(const bf16x8*)(_p + 1024);                          \
    a_[3] = *(const bf16x8*)(_p + 1536);                          \
    a_[4] = *(const bf16x8*)(_p + 2048);                          \
    a_[5] = *(const bf16x8*)(_p + 2560);                          \
    a_[6] = *(const bf16x8*)(_p + 3072);                          \
    a_[7] = *(const bf16x8*)(_p + 3584);                          \
  } while (0)

#define LDB(cb) do {                                              \
    const u16* _p = sB[cb] + bbase;                               \
    b_[0] = *(const bf16x8*)(_p);                                 \
    b_[1] = *(const bf16x8*)(_p + 512);                           \
    b_[2] = *(const bf16x8*)(_p + 1024);                          \
    b_[3] = *(const bf16x8*)(_p + 1536);                          \
  } while (0)

  // one K-tile: 32 MFMAs, acc[mf][nf] each written once (dep distance 32)
#define MFMAS do {                                                             \
    _Pragma("unroll") for (int mf = 0; mf < 8; mf++)                           \
      _Pragma("unroll") for (int nf = 0; nf < 4; nf++)                         \
        acc[mf][nf] = __builtin_amdgcn_mfma_f32_16x16x32_bf16(                 \
            a_[mf], b_[nf], acc[mf][nf], 0, 0, 0);                             \
  } while (0)

#define TILE(c, u) do {                                           \
    int _k1 = ((u) + 1) & (NT - 1);                               \
    STAGE_A((c) ^ 1, _k1);                                        \
    STAGE_B((c) ^ 1, _k1);                                        \
    LDA(c); LDB(c);                                               \
    LGKM0;                                                        \
    PRIO(1); MFMAS; PRIO(0);                                      \
    VMCNT0; BAR;                                                  \
  } while (0)

  // prologue: stage tile0 into buf0, drain, barrier (all waves' rows visible)
  STAGE_A(0, 0);
  STAGE_B(0, 0);
  VMCNT0; BAR;
  SCHED0;
  asm volatile("" ::: "memory");

#pragma unroll 1
  for (int u = 0; u < NT; u += 2) {
    TILE(0, u);
    TILE(1, u + 1);
  }

  // C/D layout: col = lane&15, row = (lane>>4)*4 + j
  // out row = m0 + wr*128 + mf*16 + (lane>>4)*4 + j;  col = n0 + wc*64 + nf*16 + (lane&15)
  float* Cp = C + (size_t)(m0 + wr * 128 + ((lane >> 4) << 2)) * N
                + n0 + wc * 64 + (lane & 15);
#pragma unroll
  for (int mf = 0; mf < 8; mf++)
#pragma unroll
    for (int nf = 0; nf < 4; nf++)
#pragma unroll
      for (int j = 0; j < 4; j++)
        Cp[(size_t)(mf * 16 + j) * N + nf * 16] = acc[mf][nf][j];
}

// ---------------- exact fp32 fallback (only if ws too small) ---------------
__global__ __launch_bounds__(256) void naive_gemm(const float* __restrict__ x,
                                                  const int* __restrict__ qw,
                                                  const int* __restrict__ qz,
                                                  const float* __restrict__ sc,
                                                  float* __restrict__ out) {
  __shared__ float xs[IN_F];
  int m = blockIdx.y;
  int n = blockIdx.x * 256 + threadIdx.x;
  for (int i = threadIdx.x; i < IN_F; i += 256) xs[i] = x[(size_t)m * IN_F + i];
  __syncthreads();
  float acc = 0.f;
  const int* qrow = qw + (size_t)n * (IN_F / 2);
  for (int g = 0; g < NGROUP; g++) {
    float z = (float)qz[n * NGROUP + g];
    float s = sc[n * NGROUP + g];
    for (int t = 0; t < 64; t++) {
      int q = qrow[g * 64 + t];
      acc += xs[g * 128 + 2 * t] * ((float)(q & 15) - z) * s;
      acc += xs[g * 128 + 2 * t + 1] * ((float)((q >> 4) & 15) - z) * s;
    }
  }
  out[(size_t)m * OUT_F + n] = acc;
}

extern "C" void kernel_launch(void* const* d_in, const int* in_sizes, int n_in,
                              void* d_out, int out_size, void* d_ws, size_t ws_size,
                              hipStream_t stream) {
  const float* x  = (const float*)d_in[0];
  const int*   qw = (const int*)d_in[1];
  const int*   qz = (const int*)d_in[2];
  const float* sc = (const float*)d_in[3];
  float* out = (float*)d_out;

  const size_t WBYTES = (size_t)OUT_F * IN_F * 2;
  const size_t XBYTES = (size_t)M_DIM * IN_F * 2;

  if (ws_size >= WBYTES + XBYTES) {
    u16* Wb = (u16*)d_ws;
    u16* Xb = (u16*)((char*)d_ws + WBYTES);
    dequant_w<<<2048, 256, 0, stream>>>(qw, qz, sc, Wb);
    cvt_x<<<2048, 256, 0, stream>>>(x, Xb);
    gemm256<<<(M_DIM / 256) * (OUT_F / 256), 512, 0, stream>>>(Xb, Wb, out);
  } else {
    naive_gemm<<<dim3(OUT_F / 256, M_DIM), 256, 0, stream>>>(x, qw, qz, sc, out);
  }
}

// Round 10
// 686.599 us; speedup vs baseline: 11.5920x; 11.5920x over previous
//
#include <hip/hip_runtime.h>
#include <hip/hip_bf16.h>

// QuantizedLinear: out[8192,11008] = x[8192,4096] @ dequant(W)^T
// Round 10: R8 baseline + memory-system fixes:
//  (a) phase close = VMCNT4;BAR, phase open = LGKM0;STAGE;MFMAs (no read-drain
//      stall before barriers; lgkm wait overlaps barrier sync),
//  (b) 2D XCD chunking (tm-window 4 x tn-groups of 8 per XCD -> concurrent
//      blocks share A AND B panels in L2),
//  (c) nontemporal C stores (keep A/B resident in L3).

#define IN_F   4096
#define OUT_F  11008
#define M_DIM  8192
#define NGROUP 32

typedef __bf16 bf16x8 __attribute__((ext_vector_type(8)));
typedef float  f32x4  __attribute__((ext_vector_type(4)));
typedef unsigned short u16;
typedef u16 u16x8v __attribute__((ext_vector_type(8)));

__device__ __forceinline__ u16 f2bf(float f) {
  union { float f; unsigned u; } v; v.f = f;
  unsigned u = v.u;
  return (u16)((u + 0x7fffu + ((u >> 16) & 1u)) >> 16);  // RNE
}

__device__ __forceinline__ void gload_lds16(const void* gsrc, void* ldst) {
  __builtin_amdgcn_global_load_lds(
      (const __attribute__((address_space(1))) void*)gsrc,
      (__attribute__((address_space(3))) void*)ldst, 16, 0, 0);
}

// ---------------- dequant: packed 4-bit -> bf16 W[out][in] -----------------
__global__ __launch_bounds__(256) void dequant_w(const int* __restrict__ qw,
                                                 const int* __restrict__ qz,
                                                 const float* __restrict__ sc,
                                                 u16* __restrict__ W) {
  const int total = (IN_F / 2) * OUT_F / 4;  // int4 chunks
  int stride = gridDim.x * blockDim.x;
  for (int idx = blockIdx.x * blockDim.x + threadIdx.x; idx < total; idx += stride) {
    int j = idx << 2;
    int o = j >> 11;
    int g = (j >> 6) & 31;
    float z = (float)qz[(o << 5) + g];
    float s = sc[(o << 5) + g];
    int4 q = ((const int4*)qw)[idx];
    int qs0 = q.x, qs1 = q.y, qs2 = q.z, qs3 = q.w;
    u16x8v w;
    w[0] = f2bf(((float)(qs0 & 15) - z) * s);
    w[1] = f2bf(((float)((qs0 >> 4) & 15) - z) * s);
    w[2] = f2bf(((float)(qs1 & 15) - z) * s);
    w[3] = f2bf(((float)((qs1 >> 4) & 15) - z) * s);
    w[4] = f2bf(((float)(qs2 & 15) - z) * s);
    w[5] = f2bf(((float)((qs2 >> 4) & 15) - z) * s);
    w[6] = f2bf(((float)(qs3 & 15) - z) * s);
    w[7] = f2bf(((float)((qs3 >> 4) & 15) - z) * s);
    ((u16x8v*)W)[idx] = w;
  }
}

// ---------------- x fp32 -> bf16 -------------------------------------------
__global__ __launch_bounds__(256) void cvt_x(const float* __restrict__ x,
                                             u16* __restrict__ Xb) {
  const int total = M_DIM * IN_F / 8;
  int stride = gridDim.x * blockDim.x;
  for (int idx = blockIdx.x * blockDim.x + threadIdx.x; idx < total; idx += stride) {
    float4 a = ((const float4*)x)[idx * 2];
    float4 b = ((const float4*)x)[idx * 2 + 1];
    u16x8v v;
    v[0] = f2bf(a.x); v[1] = f2bf(a.y); v[2] = f2bf(a.z); v[3] = f2bf(a.w);
    v[4] = f2bf(b.x); v[5] = f2bf(b.y); v[6] = f2bf(b.z); v[7] = f2bf(b.w);
    ((u16x8v*)Xb)[idx] = v;
  }
}

// ---------------- 256x256 bf16 GEMM, 2 phases/K-tile: C = A * B^T ----------
// 8 waves 2Mx4N, wave tile 128x64. A-half mh = rows [mh*128 + wr*64);
// B-half nh = cols [nh*128 + wc*32).
// PhA(u): quadrants (0,0),(0,1); stage A1(u+1)->c^1, A0(u+2)->c; roll a_<-A1(u).
// PhB(u): quadrants (1,0),(1,1); stage B0,B1(u+2)->c; reload b0_,b1_<-B(u+1),
//         roll a_<-A0(u+1).
// Phase shape: LGKM0 (drain in-flight rolls; MUST precede stages that
// overwrite rolled-from regions) ; STAGEs ; MFMAs+rolls ; VMCNT4 ; BAR.

#define BAR       __builtin_amdgcn_s_barrier()
#define SCHED0    __builtin_amdgcn_sched_barrier(0)
#define LGKM0     asm volatile("s_waitcnt lgkmcnt(0)" ::: "memory")
#define VMCNT0    asm volatile("s_waitcnt vmcnt(0)" ::: "memory")
#define VMCNT4    asm volatile("s_waitcnt vmcnt(4)" ::: "memory")
#define PRIO(p)   __builtin_amdgcn_s_setprio(p)

__global__ __launch_bounds__(512, 2) void gemm256(const u16* __restrict__ A,
                                                  const u16* __restrict__ B,
                                                  float* __restrict__ C) {
  constexpr int K = IN_F, N = OUT_F;
  constexpr int NT = K / 64;  // 64 K-tiles
  __shared__ __align__(16) u16 sA[2][256 * 64];
  __shared__ __align__(16) u16 sB[2][256 * 64];

  // 2D XCD chunking: NTM = 32 = 8 XCDs x 4 tm rows; each XCD walks its 4 tm
  // rows in tn-groups of 8 (last group 3). Concurrent blocks on an XCD share
  // 4 A-panels + 8 B-panels (L2-sized) instead of 1 A + 32 B.
  int bid = blockIdx.x;
  int xcd = bid & 7;
  int l   = bid >> 3;                 // 0..171
  int tm_l, tn;
  if (l < 160) { int g = l >> 5, r = l & 31; tm_l = r & 3; tn = g * 8 + (r >> 2); }
  else         { int r = l - 160;            tm_l = r & 3; tn = 40 + (r >> 2); }
  int tm = xcd * 4 + tm_l;
  int m0 = tm * 256, n0 = tn * 256;

  int tid  = threadIdx.x;
  int lane = tid & 63;
  int wave = tid >> 6;
  int wr = wave >> 2, wc = wave & 3;

  // staging: thread covers row (tid>>3), phys 16B slot tid&7.
  // phys slot s at row r holds global col-slot s^(r&7)  (involution).
  int rstage = tid >> 3;                               // 0..63
  int gslot  = ((tid & 7) ^ (rstage & 7)) << 3;        // global col elem
  int ldsoff = rstage * 64 + ((tid & 7) << 3);         // linear LDS elem
  const u16* Ag = A + (size_t)(m0 + rstage) * K + gslot;
  const u16* Bg = B + (size_t)(n0 + rstage) * K + gslot;

#define STAGE_A(cb, h, kt) do {                                   \
    const u16* _g = Ag + (size_t)(h) * 128 * K + (kt) * 64;       \
    u16* _l = sA[cb] + (h) * 128 * 64 + ldsoff;                   \
    gload_lds16(_g, _l);                                          \
    gload_lds16(_g + (size_t)64 * K, _l + 64 * 64);               \
  } while (0)

#define STAGE_B(cb, h, kt) do {                                   \
    const u16* _g = Bg + (size_t)(h) * 128 * K + (kt) * 64;       \
    u16* _l = sB[cb] + (h) * 128 * 64 + ldsoff;                   \
    gload_lds16(_g, _l);                                          \
    gload_lds16(_g + (size_t)64 * K, _l + 64 * 64);               \
  } while (0)

  // fragment reads: lane reads row base+(lane&15), k-quad q=lane>>4, slice ks.
  // phys 16B slot = (ks*4+q) ^ (lane&7)   (row&7 == lane&7: all row bases %8==0)
  int q8  = lane >> 4;
  int sl0 = ((q8 ^ (lane & 7)) << 3);            // ks=0, elems
  int sl1 = (((q8 | 4) ^ (lane & 7)) << 3);      // ks=1
  int abase = (wr * 64 + (lane & 15)) * 64;      // within A-half
  int bbase = (wc * 32 + (lane & 15)) * 64;      // within B-half

  bf16x8 a_[8], b0_[4], b1_[4];
  f32x4 acc[8][4] = {};

#define LDA(cb, mh) do {                                          \
    const u16* _p = sA[cb] + abase + (mh) * 8192;                 \
    a_[0] = *(const bf16x8*)(_p + sl0);                           \
    a_[1] = *(const bf16x8*)(_p + sl1);                           \
    a_[2] = *(const bf16x8*)(_p + 1024 + sl0);                    \
    a_[3] = *(const bf16x8*)(_p + 1024 + sl1);                    \
    a_[4] = *(const bf16x8*)(_p + 2048 + sl0);                    \
    a_[5] = *(const bf16x8*)(_p + 2048 + sl1);                    \
    a_[6] = *(const bf16x8*)(_p + 3072 + sl0);                    \
    a_[7] = *(const bf16x8*)(_p + 3072 + sl1);                    \
  } while (0)

#define LDB(cb, nh, dst) do {                                     \
    const u16* _p = sB[cb] + bbase + (nh) * 8192;                 \
    dst[0] = *(const bf16x8*)(_p + sl0);                          \
    dst[1] = *(const bf16x8*)(_p + sl1);                          \
    dst[2] = *(const bf16x8*)(_p + 1024 + sl0);                   \
    dst[3] = *(const bf16x8*)(_p + 1024 + sl1);                   \
  } while (0)

  // ks-OUTER MFMA ordering (dep distance 8).
#define QUAD(mh, nh, bq) do {                                                  \
    _Pragma("unroll") for (int mf = 0; mf < 4; mf++)                           \
      _Pragma("unroll") for (int nf = 0; nf < 2; nf++)                         \
        acc[(mh)*4+mf][(nh)*2+nf] = __builtin_amdgcn_mfma_f32_16x16x32_bf16(   \
            a_[mf*2+0], bq[nf*2+0], acc[(mh)*4+mf][(nh)*2+nf], 0, 0, 0);       \
    _Pragma("unroll") for (int mf = 0; mf < 4; mf++)                           \
      _Pragma("unroll") for (int nf = 0; nf < 2; nf++)                         \
        acc[(mh)*4+mf][(nh)*2+nf] = __builtin_amdgcn_mfma_f32_16x16x32_bf16(   \
            a_[mf*2+1], bq[nf*2+1], acc[(mh)*4+mf][(nh)*2+nf], 0, 0, 0);       \
  } while (0)

  // rolling A-prefetch folded into the ks=1 pass.
#define QUAD_ROLLA(mh, nh, bq, rp) do {                                        \
    _Pragma("unroll") for (int mf = 0; mf < 4; mf++)                           \
      _Pragma("unroll") for (int nf = 0; nf < 2; nf++)                         \
        acc[(mh)*4+mf][(nh)*2+nf] = __builtin_amdgcn_mfma_f32_16x16x32_bf16(   \
            a_[mf*2+0], bq[nf*2+0], acc[(mh)*4+mf][(nh)*2+nf], 0, 0, 0);       \
    _Pragma("unroll") for (int mf = 0; mf < 4; mf++) {                         \
      _Pragma("unroll") for (int nf = 0; nf < 2; nf++)                         \
        acc[(mh)*4+mf][(nh)*2+nf] = __builtin_amdgcn_mfma_f32_16x16x32_bf16(   \
            a_[mf*2+1], bq[nf*2+1], acc[(mh)*4+mf][(nh)*2+nf], 0, 0, 0);       \
      a_[mf*2+0] = *(const bf16x8*)((rp) + mf * 1024 + sl0);                   \
      a_[mf*2+1] = *(const bf16x8*)((rp) + mf * 1024 + sl1);                   \
    }                                                                          \
  } while (0)

  // Two phases per K-tile (buf c = u&1). LGKM0 opens each phase (drains the
  // in-flight rolls/reloads issued pre-barrier; overlaps barrier wait) and
  // MUST precede the stages (WAR: PhA's A0-stage overwrites the region the
  // previous PhB's rolls read).
#define TILE2(c, u) do {                                          \
    int _k1 = ((u) + 1) & (NT - 1), _k2 = ((u) + 2) & (NT - 1);   \
    /* PhA: (0,0),(0,1) with a_=A0(u) */                          \
    LGKM0;                                                        \
    STAGE_A((c) ^ 1, 1, _k1);                                     \
    STAGE_A(c, 0, _k2);                                           \
    PRIO(1);                                                      \
    QUAD(0, 0, b0_);                                              \
    QUAD_ROLLA(0, 1, b1_, sA[c] + abase + 8192);                  \
    PRIO(0); VMCNT4; BAR;                                         \
    /* PhB: (1,0),(1,1) with a_=A1(u) */                          \
    LGKM0;                                                        \
    STAGE_B(c, 0, _k2);                                           \
    STAGE_B(c, 1, _k2);                                           \
    PRIO(1);                                                      \
    QUAD(1, 0, b0_);                                              \
    LDB((c) ^ 1, 0, b0_);                                         \
    QUAD_ROLLA(1, 1, b1_, sA[(c) ^ 1] + abase);                   \
    LDB((c) ^ 1, 1, b1_);                                         \
    PRIO(0); VMCNT4; BAR;                                         \
  } while (0)

  // prologue: stage tile0 (A0,A1,B0,B1) + A0(1); drain ALL, barrier, preload
  // frags; then stage B(1) so exactly 4 loads are in flight entering the loop.
  STAGE_A(0, 0, 0); STAGE_A(0, 1, 0);
  STAGE_B(0, 0, 0); STAGE_B(0, 1, 0);
  STAGE_A(1, 0, 1);
  VMCNT0; BAR;
  SCHED0;
  asm volatile("" ::: "memory");
  LDA(0, 0);
  LDB(0, 0, b0_);
  LDB(0, 1, b1_);
  STAGE_B(1, 0, 1); STAGE_B(1, 1, 1);

#pragma unroll 1
  for (int u = 0; u < NT; u += 2) {
    TILE2(0, u);
    TILE2(1, u + 1);
  }

  // C/D layout: col = lane&15, row = (lane>>4)*4 + j. Nontemporal stores
  // (C is write-once; keep A/B resident in L3).
  float* Cp = C + (size_t)(m0 + wr * 64 + ((lane >> 4) << 2)) * N
                + n0 + wc * 32 + (lane & 15);
#pragma unroll
  for (int m = 0; m < 8; m++) {
    int roff = (m >> 2) * 128 + (m & 3) * 16;
#pragma unroll
    for (int n = 0; n < 4; n++) {
      int coff = (n >> 1) * 128 + (n & 1) * 16;
#pragma unroll
      for (int j = 0; j < 4; j++)
        __builtin_nontemporal_store(acc[m][n][j],
                                    &Cp[(size_t)(roff + j) * N + coff]);
    }
  }
}

// ---------------- exact fp32 fallback (only if ws too small) ---------------
__global__ __launch_bounds__(256) void naive_gemm(const float* __restrict__ x,
                                                  const int* __restrict__ qw,
                                                  const int* __restrict__ qz,
                                                  const float* __restrict__ sc,
                                                  float* __restrict__ out) {
  __shared__ float xs[IN_F];
  int m = blockIdx.y;
  int n = blockIdx.x * 256 + threadIdx.x;
  for (int i = threadIdx.x; i < IN_F; i += 256) xs[i] = x[(size_t)m * IN_F + i];
  __syncthreads();
  float acc = 0.f;
  const int* qrow = qw + (size_t)n * (IN_F / 2);
  for (int g = 0; g < NGROUP; g++) {
    float z = (float)qz[n * NGROUP + g];
    float s = sc[n * NGROUP + g];
    for (int t = 0; t < 64; t++) {
      int q = qrow[g * 64 + t];
      acc += xs[g * 128 + 2 * t] * ((float)(q & 15) - z) * s;
      acc += xs[g * 128 + 2 * t + 1] * ((float)((q >> 4) & 15) - z) * s;
    }
  }
  out[(size_t)m * OUT_F + n] = acc;
}

extern "C" void kernel_launch(void* const* d_in, const int* in_sizes, int n_in,
                              void* d_out, int out_size, void* d_ws, size_t ws_size,
                              hipStream_t stream) {
  const float* x  = (const float*)d_in[0];
  const int*   qw = (const int*)d_in[1];
  const int*   qz = (const int*)d_in[2];
  const float* sc = (const float*)d_in[3];
  float* out = (float*)d_out;

  const size_t WBYTES = (size_t)OUT_F * IN_F * 2;
  const size_t XBYTES = (size_t)M_DIM * IN_F * 2;

  if (ws_size >= WBYTES + XBYTES) {
    u16* Wb = (u16*)d_ws;
    u16* Xb = (u16*)((char*)d_ws + WBYTES);
    dequant_w<<<2048, 256, 0, stream>>>(qw, qz, sc, Wb);
    cvt_x<<<2048, 256, 0, stream>>>(x, Xb);
    gemm256<<<(M_DIM / 256) * (OUT_F / 256), 512, 0, stream>>>(Xb, Wb, out);
  } else {
    naive_gemm<<<dim3(OUT_F / 256, M_DIM), 256, 0, stream>>>(x, qw, qz, sc, out);
  }
}